// Round 4
// baseline (286.466 us; speedup 1.0000x reference)
//
#include <hip/hip_runtime.h>
#include <hip/hip_bf16.h>

// MHA forward: B=2, H=16, S=2048, D=1024, d_k=64, causal, RoPE(theta=1e4)
// Pipeline: cvt fp32->bf16 -> QKV GEMM (bf16 MFMA, V written transposed)
//           -> RoPE -> flash attention -> out GEMM (fp32 out)

typedef __bf16 bf16x8 __attribute__((ext_vector_type(8)));
typedef __bf16 bf16x4 __attribute__((ext_vector_type(4)));
typedef float f32x4 __attribute__((ext_vector_type(4)));
typedef unsigned short ushort8 __attribute__((ext_vector_type(8)));

#define BATCH 2
#define SEQ 2048
#define NH 16
#define DK 64
#define DM 1024
#define BH (BATCH*NH)
#define M_TOT (BATCH*SEQ)   // 4096

// ---------------- fp32 -> bf16 convert ----------------
__global__ void cvt_kernel(const float* __restrict__ s, __bf16* __restrict__ d, int n) {
    int i = (blockIdx.x * blockDim.x + threadIdx.x) * 4;
    if (i >= n) return;
    float4 v = *(const float4*)(s + i);
    bf16x4 o;
    o[0] = (__bf16)v.x; o[1] = (__bf16)v.y; o[2] = (__bf16)v.z; o[3] = (__bf16)v.w;
    *(bf16x4*)(d + i) = o;
}

// ---------------- GEMM core: C[128x128] = A[128xK] * W[128xK]^T ----------------
// A row-major [M][K], W row-major [N][K] (Linear weight layout), both bf16.
// 256 threads = 4 waves in 2x2, each wave 64x64 = 4x4 fragments of 16x16.
#define LDT 40   // LDS row stride (elements): 80B rows -> 2-way bank conflicts only

__device__ __forceinline__ void gemm_tile_compute(
    const __bf16* __restrict__ A, const __bf16* __restrict__ W,
    int m0, int n0, int K, __bf16* sA, __bf16* sB, f32x4 (&acc)[4][4])
{
    const int t = threadIdx.x;
    const int lane = t & 63, wid = t >> 6;
    const int wr = wid >> 1, wc = wid & 1;
    const int g = lane >> 4, l15 = lane & 15;

    f32x4 zero = {0.f, 0.f, 0.f, 0.f};
#pragma unroll
    for (int mt = 0; mt < 4; ++mt)
#pragma unroll
        for (int nt = 0; nt < 4; ++nt) acc[mt][nt] = zero;

    for (int k0 = 0; k0 < K; k0 += 32) {
        __syncthreads();
#pragma unroll
        for (int cc = 0; cc < 2; ++cc) {
            int c = t + cc * 256;            // 0..511
            int r = c >> 2, kk = (c & 3) << 3;
            *(ushort8*)&sA[r * LDT + kk] = *(const ushort8*)&A[(size_t)(m0 + r) * K + k0 + kk];
            *(ushort8*)&sB[r * LDT + kk] = *(const ushort8*)&W[(size_t)(n0 + r) * K + k0 + kk];
        }
        __syncthreads();
        bf16x8 af[4], bfr[4];
#pragma unroll
        for (int mt = 0; mt < 4; ++mt)
            af[mt] = *(const bf16x8*)&sA[(wr * 64 + mt * 16 + l15) * LDT + g * 8];
#pragma unroll
        for (int nt = 0; nt < 4; ++nt)
            bfr[nt] = *(const bf16x8*)&sB[(wc * 64 + nt * 16 + l15) * LDT + g * 8];
#pragma unroll
        for (int mt = 0; mt < 4; ++mt)
#pragma unroll
            for (int nt = 0; nt < 4; ++nt)
                acc[mt][nt] = __builtin_amdgcn_mfma_f32_16x16x32_bf16(af[mt], bfr[nt], acc[mt][nt], 0, 0, 0);
    }
}

// QKV GEMM: z=0 -> Q [B,H,S,dk], z=1 -> K [B,H,S,dk], z=2 -> V^T [B,H,dk,S]
__global__ __launch_bounds__(256) void gemm_qkv(
    const __bf16* __restrict__ xb,
    const __bf16* __restrict__ wq, const __bf16* __restrict__ wk, const __bf16* __restrict__ wv,
    __bf16* __restrict__ Qb, __bf16* __restrict__ Kb, __bf16* __restrict__ VTb)
{
    __shared__ __bf16 sA[128 * LDT], sB[128 * LDT];
    const int z = blockIdx.z;
    const __bf16* W = (z == 0) ? wq : ((z == 1) ? wk : wv);
    f32x4 acc[4][4];
    const int m0 = blockIdx.y * 128, n0 = blockIdx.x * 128;
    gemm_tile_compute(xb, W, m0, n0, DM, sA, sB, acc);

    const int t = threadIdx.x, lane = t & 63, wid = t >> 6;
    const int wr = wid >> 1, wc = wid & 1, g = lane >> 4, l15 = lane & 15;
    __bf16* QK = (z == 0) ? Qb : Kb;
#pragma unroll
    for (int mt = 0; mt < 4; ++mt)
#pragma unroll
        for (int nt = 0; nt < 4; ++nt)
#pragma unroll
            for (int r = 0; r < 4; ++r) {
                int m = m0 + wr * 64 + mt * 16 + g * 4 + r;   // (b, s)
                int n = n0 + wc * 64 + nt * 16 + l15;         // (h, d)
                int b = m >> 11, s = m & 2047, h = n >> 6, d = n & 63;
                __bf16 v = (__bf16)acc[mt][nt][r];
                if (z < 2)
                    QK[(((size_t)(b * NH + h)) * SEQ + s) * DK + d] = v;
                else
                    VTb[(((size_t)(b * NH + h)) * DK + d) * SEQ + s] = v;
            }
}

// Output GEMM: out[M,1024] fp32 = AO[M,1024]bf16 @ Wo^T
__global__ __launch_bounds__(256) void gemm_out(
    const __bf16* __restrict__ AO, const __bf16* __restrict__ wo, float* __restrict__ out)
{
    __shared__ __bf16 sA[128 * LDT], sB[128 * LDT];
    f32x4 acc[4][4];
    const int m0 = blockIdx.y * 128, n0 = blockIdx.x * 128;
    gemm_tile_compute(AO, wo, m0, n0, DM, sA, sB, acc);

    const int t = threadIdx.x, lane = t & 63, wid = t >> 6;
    const int wr = wid >> 1, wc = wid & 1, g = lane >> 4, l15 = lane & 15;
#pragma unroll
    for (int mt = 0; mt < 4; ++mt)
#pragma unroll
        for (int nt = 0; nt < 4; ++nt)
#pragma unroll
            for (int r = 0; r < 4; ++r) {
                int m = m0 + wr * 64 + mt * 16 + g * 4 + r;
                int n = n0 + wc * 64 + nt * 16 + l15;
                out[(size_t)m * DM + n] = acc[mt][nt][r];
            }
}

// ---------------- RoPE (in-place on Q,K bf16 [B,H,S,dk]) ----------------
__global__ __launch_bounds__(256) void rope_kernel(
    __bf16* __restrict__ Qb, __bf16* __restrict__ Kb, const int* __restrict__ pos)
{
    __shared__ float ctab[32], stab[32];
    const int s = blockIdx.x;       // 0..SEQ-1
    const int t = threadIdx.x;
    if (t < 32) {
        // inv_freq = 10000^(-t/32) = exp2(-t/32 * log2(10000))
        float invf = exp2f(-13.287712379549449f * (float)t * (1.0f / 32.0f));
        float ang = (float)pos[s] * invf;
        float sn, cs;
        sincosf(ang, &sn, &cs);
        ctab[t] = cs; stab[t] = sn;
    }
    __syncthreads();
#pragma unroll
    for (int u = 0; u < 8; ++u) {
        int id = u * 256 + t;              // 0..2047 : [arr][bh][i]
        int i = id & 31;
        int bh = (id >> 5) & 31;
        __bf16* P = (id >> 10) ? Kb : Qb;
        __bf16* p = P + ((size_t)bh * SEQ + s) * DK + i * 2;
        float x1 = (float)p[0], x2 = (float)p[1];
        float c = ctab[i], sn = stab[i];
        p[0] = (__bf16)(x1 * c - x2 * sn);
        p[1] = (__bf16)(x1 * sn + x2 * c);
    }
}

// ---------------- Flash attention ----------------
// grid: (qt=S/64, bh=32). 256 threads = 4 waves, wave w owns q rows [w*16, w*16+16).
// K tile [64][dk] and V^T tile [dk][64] staged in LDS (row stride 72 -> 2-way conflicts).
#define LDK 72

__global__ __launch_bounds__(256) void attn_kernel(
    const __bf16* __restrict__ Qb, const __bf16* __restrict__ Kb,
    const __bf16* __restrict__ VTb, __bf16* __restrict__ AO)
{
    __shared__ __bf16 sK[64 * LDK];        // [kv][d]
    __shared__ __bf16 sV[64 * LDK];        // [d][kv]
    __shared__ __bf16 sP[4 * 16 * LDK];    // per-wave [16 q][64 kv]

    const int qt = blockIdx.x, bh = blockIdx.y;
    const int t = threadIdx.x, lane = t & 63, wid = t >> 6;
    const int g = lane >> 4, l15 = lane & 15;

    const size_t baseQK = (size_t)bh * SEQ * DK;
    const size_t baseVT = (size_t)bh * DK * SEQ;

    // Q fragments (held in registers across the whole kv loop)
    bf16x8 qf[2];
    {
        const __bf16* qp = Qb + baseQK + (size_t)(qt * 64 + wid * 16 + l15) * DK;
        qf[0] = *(const bf16x8*)(qp + g * 8);
        qf[1] = *(const bf16x8*)(qp + 32 + g * 8);
    }

    f32x4 zero = {0.f, 0.f, 0.f, 0.f};
    f32x4 oacc[4];
#pragma unroll
    for (int dt = 0; dt < 4; ++dt) oacc[dt] = zero;
    float mrow[4], lrow[4];
#pragma unroll
    for (int r = 0; r < 4; ++r) { mrow[r] = -3e38f; lrow[r] = 0.f; }

    __bf16* myP = sP + wid * 16 * LDK;

    for (int kt = 0; kt <= qt; ++kt) {
        __syncthreads();
        // stage K tile [64 kv][64 d] + V^T tile [64 d][64 kv]
        // 64 rows x 64 bf16 = 512 chunks of 8 elems each buffer -> 2 per thread
#pragma unroll
        for (int cc = 0; cc < 2; ++cc) {
            int c = t + cc * 256;            // 0..511
            int r = c >> 3, kk = (c & 7) << 3;
            *(ushort8*)&sK[r * LDK + kk] =
                *(const ushort8*)(Kb + baseQK + (size_t)(kt * 64 + r) * DK + kk);
            *(ushort8*)&sV[r * LDK + kk] =
                *(const ushort8*)(VTb + baseVT + (size_t)r * SEQ + kt * 64 + kk);
        }
        __syncthreads();

        // S = Q K^T (scaled), 4 col-tiles of 16
        f32x4 sacc[4];
#pragma unroll
        for (int nt = 0; nt < 4; ++nt) {
            sacc[nt] = zero;
#pragma unroll
            for (int ks = 0; ks < 2; ++ks) {
                bf16x8 kf = *(const bf16x8*)&sK[(nt * 16 + l15) * LDK + ks * 32 + g * 8];
                sacc[nt] = __builtin_amdgcn_mfma_f32_16x16x32_bf16(qf[ks], kf, sacc[nt], 0, 0, 0);
            }
        }
#pragma unroll
        for (int nt = 0; nt < 4; ++nt)
#pragma unroll
            for (int r = 0; r < 4; ++r) {
                float sv = sacc[nt][r] * 0.125f;
                if (kt == qt) {
                    int c_local = nt * 16 + l15;
                    int q_local = wid * 16 + g * 4 + r;
                    if (c_local > q_local) sv = -3e38f;
                }
                sacc[nt][r] = sv;
            }

        // online softmax per row (row r lives on the 16 lanes of group g)
#pragma unroll
        for (int r = 0; r < 4; ++r) {
            float tm = fmaxf(fmaxf(sacc[0][r], sacc[1][r]), fmaxf(sacc[2][r], sacc[3][r]));
#pragma unroll
            for (int msk = 1; msk < 16; msk <<= 1) tm = fmaxf(tm, __shfl_xor(tm, msk));
            float mnew = fmaxf(mrow[r], tm);
            float sc = __expf(mrow[r] - mnew);
            float rs = 0.f;
#pragma unroll
            for (int nt = 0; nt < 4; ++nt) {
                float p = __expf(sacc[nt][r] - mnew);
                sacc[nt][r] = p;
                rs += p;
            }
#pragma unroll
            for (int msk = 1; msk < 16; msk <<= 1) rs += __shfl_xor(rs, msk);
            lrow[r] = lrow[r] * sc + rs;
            mrow[r] = mnew;
#pragma unroll
            for (int dt = 0; dt < 4; ++dt) oacc[dt][r] *= sc;
        }

        // P -> LDS (bf16), then PV
#pragma unroll
        for (int nt = 0; nt < 4; ++nt)
#pragma unroll
            for (int r = 0; r < 4; ++r)
                myP[(g * 4 + r) * LDK + nt * 16 + l15] = (__bf16)sacc[nt][r];
        __syncthreads();

#pragma unroll
        for (int ks = 0; ks < 2; ++ks) {
            bf16x8 pf = *(const bf16x8*)&myP[l15 * LDK + ks * 32 + g * 8];
#pragma unroll
            for (int dt = 0; dt < 4; ++dt) {
                bf16x8 vf = *(const bf16x8*)&sV[(dt * 16 + l15) * LDK + ks * 32 + g * 8];
                oacc[dt] = __builtin_amdgcn_mfma_f32_16x16x32_bf16(pf, vf, oacc[dt], 0, 0, 0);
            }
        }
    }

    // epilogue: O /= l, write to AO [b][s][h*64+d]
    const int b = bh >> 4, h = bh & 15;
#pragma unroll
    for (int r = 0; r < 4; ++r) {
        float inv = 1.0f / lrow[r];
        int srow = qt * 64 + wid * 16 + g * 4 + r;
        size_t obase = ((size_t)b * SEQ + srow) * DM + h * DK;
#pragma unroll
        for (int dt = 0; dt < 4; ++dt)
            AO[obase + dt * 16 + l15] = (__bf16)(oacc[dt][r] * inv);
    }
}

// ---------------- launch ----------------
extern "C" void kernel_launch(void* const* d_in, const int* in_sizes, int n_in,
                              void* d_out, int out_size, void* d_ws, size_t ws_size,
                              hipStream_t stream) {
    (void)in_sizes; (void)n_in; (void)out_size; (void)ws_size;
    const float* x  = (const float*)d_in[0];
    const int*  pos = (const int*)d_in[1];
    const float* Wq = (const float*)d_in[2];
    const float* Wk = (const float*)d_in[3];
    const float* Wv = (const float*)d_in[4];
    const float* Wo = (const float*)d_in[5];
    float* out = (float*)d_out;

    char* ws = (char*)d_ws;
    __bf16* xb  = (__bf16*)ws; ws += (size_t)M_TOT * DM * 2;
    __bf16* wqb = (__bf16*)ws; ws += (size_t)DM * DM * 2;
    __bf16* wkb = (__bf16*)ws; ws += (size_t)DM * DM * 2;
    __bf16* wvb = (__bf16*)ws; ws += (size_t)DM * DM * 2;
    __bf16* wob = (__bf16*)ws; ws += (size_t)DM * DM * 2;
    __bf16* Qb  = (__bf16*)ws; ws += (size_t)BH * SEQ * DK * 2;
    __bf16* Kb  = (__bf16*)ws; ws += (size_t)BH * SEQ * DK * 2;
    __bf16* VTb = (__bf16*)ws; ws += (size_t)BH * SEQ * DK * 2;
    __bf16* AOb = (__bf16*)ws; ws += (size_t)M_TOT * DM * 2;

    const int nx = M_TOT * DM, nw = DM * DM;
    cvt_kernel<<<nx / 4 / 256, 256, 0, stream>>>(x,  xb,  nx);
    cvt_kernel<<<nw / 4 / 256, 256, 0, stream>>>(Wq, wqb, nw);
    cvt_kernel<<<nw / 4 / 256, 256, 0, stream>>>(Wk, wkb, nw);
    cvt_kernel<<<nw / 4 / 256, 256, 0, stream>>>(Wv, wvb, nw);
    cvt_kernel<<<nw / 4 / 256, 256, 0, stream>>>(Wo, wob, nw);

    gemm_qkv<<<dim3(DM / 128, M_TOT / 128, 3), 256, 0, stream>>>(xb, wqb, wkb, wvb, Qb, Kb, VTb);
    rope_kernel<<<SEQ, 256, 0, stream>>>(Qb, Kb, pos);
    attn_kernel<<<dim3(SEQ / 64, BH), 256, 0, stream>>>(Qb, Kb, VTb, AOb);
    gemm_out<<<dim3(DM / 128, M_TOT / 128), 256, 0, stream>>>(AOb, wob, out);
}

// Round 5
// 229.432 us; speedup vs baseline: 1.2486x; 1.2486x over previous
//
#include <hip/hip_runtime.h>
#include <hip/hip_bf16.h>

// MHA forward: B=2, H=16, S=2048, D=1024, d_k=64, causal, RoPE(theta=1e4)
// R4 -> R5 changes (theory-first):
//  - attn: XOR-swizzled linear-128B-row LDS tiles (kills ~8-way b128 conflicts),
//          pair-balanced q-tile mapping {x, 31-x} (kills tail imbalance),
//          per-wave sP (drop one barrier/iter).
//  - gemm: global_load_lds width-16 staging into linear [128][32] LDS (m97 recipe).
//  - cvt: 4 weight converts merged into one launch.

typedef __bf16 bf16x8 __attribute__((ext_vector_type(8)));
typedef __bf16 bf16x4 __attribute__((ext_vector_type(4)));
typedef float f32x4 __attribute__((ext_vector_type(4)));
typedef unsigned short ushort8 __attribute__((ext_vector_type(8)));

#define BATCH 2
#define SEQ 2048
#define NH 16
#define DK 64
#define DM 1024
#define BH (BATCH*NH)
#define M_TOT (BATCH*SEQ)   // 4096
#define NQT (SEQ/64)        // 32 q-tiles

__device__ __forceinline__ void gload16(const void* g, void* l) {
    // async global->LDS, 16B/lane; LDS dest = wave-uniform base + lane*16
    __builtin_amdgcn_global_load_lds((const __attribute__((address_space(1))) void*)g,
                                     (__attribute__((address_space(3))) void*)l, 16, 0, 0);
}

// ---------------- fp32 -> bf16 converts ----------------
__global__ void cvt_kernel(const float* __restrict__ s, __bf16* __restrict__ d, int n) {
    int i = (blockIdx.x * blockDim.x + threadIdx.x) * 4;
    if (i >= n) return;
    float4 v = *(const float4*)(s + i);
    bf16x4 o;
    o[0] = (__bf16)v.x; o[1] = (__bf16)v.y; o[2] = (__bf16)v.z; o[3] = (__bf16)v.w;
    *(bf16x4*)(d + i) = o;
}

__global__ void cvt4_kernel(const float* __restrict__ s0, const float* __restrict__ s1,
                            const float* __restrict__ s2, const float* __restrict__ s3,
                            __bf16* __restrict__ d0, __bf16* __restrict__ d1,
                            __bf16* __restrict__ d2, __bf16* __restrict__ d3, int n) {
    const int z = blockIdx.y;
    const float* s = (z == 0) ? s0 : (z == 1) ? s1 : (z == 2) ? s2 : s3;
    __bf16* d = (z == 0) ? d0 : (z == 1) ? d1 : (z == 2) ? d2 : d3;
    int i = (blockIdx.x * blockDim.x + threadIdx.x) * 4;
    if (i >= n) return;
    float4 v = *(const float4*)(s + i);
    bf16x4 o;
    o[0] = (__bf16)v.x; o[1] = (__bf16)v.y; o[2] = (__bf16)v.z; o[3] = (__bf16)v.w;
    *(bf16x4*)(d + i) = o;
}

// ---------------- GEMM core: C[128x128] = A[128xK] * W[128xK]^T ----------------
// m97 structure: linear [128][32] bf16 LDS, global_load_lds width-16 staging.
__device__ __forceinline__ void gemm_tile_compute(
    const __bf16* __restrict__ A, const __bf16* __restrict__ W,
    int m0, int n0, int K, __bf16* sA, __bf16* sB, f32x4 (&acc)[4][4])
{
    const int t = threadIdx.x;
    const int lane = t & 63, wid = t >> 6;
    const int wr = wid >> 1, wc = wid & 1;
    const int g = lane >> 4, l15 = lane & 15;

    f32x4 zero = {0.f, 0.f, 0.f, 0.f};
#pragma unroll
    for (int mt = 0; mt < 4; ++mt)
#pragma unroll
        for (int nt = 0; nt < 4; ++nt) acc[mt][nt] = zero;

    for (int k0 = 0; k0 < K; k0 += 32) {
        __syncthreads();                       // prev iter's ds_reads complete
#pragma unroll
        for (int rnd = 0; rnd < 2; ++rnd) {
            int s = rnd * 256 + t;             // slot 0..511: row = s>>2, 16B-chunk = s&3
            int row = s >> 2, ch = s & 3;
            __bf16* dstA = sA + (rnd * 256 + wid * 64) * 8;   // wave-uniform base
            __bf16* dstB = sB + (rnd * 256 + wid * 64) * 8;
            gload16(A + (size_t)(m0 + row) * K + k0 + ch * 8, dstA);
            gload16(W + (size_t)(n0 + row) * K + k0 + ch * 8, dstB);
        }
        __syncthreads();                       // barrier drains vmcnt -> LDS valid
        bf16x8 af[4], bfr[4];
#pragma unroll
        for (int mt = 0; mt < 4; ++mt)
            af[mt] = *(const bf16x8*)&sA[(wr * 64 + mt * 16 + l15) * 32 + g * 8];
#pragma unroll
        for (int nt = 0; nt < 4; ++nt)
            bfr[nt] = *(const bf16x8*)&sB[(wc * 64 + nt * 16 + l15) * 32 + g * 8];
#pragma unroll
        for (int mt = 0; mt < 4; ++mt)
#pragma unroll
            for (int nt = 0; nt < 4; ++nt)
                acc[mt][nt] = __builtin_amdgcn_mfma_f32_16x16x32_bf16(af[mt], bfr[nt], acc[mt][nt], 0, 0, 0);
    }
}

// QKV GEMM: z=0 -> Q [B,H,S,dk], z=1 -> K [B,H,S,dk], z=2 -> V^T [B,H,dk,S]
__global__ __launch_bounds__(256) void gemm_qkv(
    const __bf16* __restrict__ xb,
    const __bf16* __restrict__ wq, const __bf16* __restrict__ wk, const __bf16* __restrict__ wv,
    __bf16* __restrict__ Qb, __bf16* __restrict__ Kb, __bf16* __restrict__ VTb)
{
    __shared__ __align__(16) __bf16 sA[128 * 32], sB[128 * 32];
    const int z = blockIdx.z;
    const __bf16* W = (z == 0) ? wq : ((z == 1) ? wk : wv);
    f32x4 acc[4][4];
    const int m0 = blockIdx.y * 128, n0 = blockIdx.x * 128;
    gemm_tile_compute(xb, W, m0, n0, DM, sA, sB, acc);

    const int t = threadIdx.x, lane = t & 63, wid = t >> 6;
    const int wr = wid >> 1, wc = wid & 1, g = lane >> 4, l15 = lane & 15;
    __bf16* QK = (z == 0) ? Qb : Kb;
#pragma unroll
    for (int mt = 0; mt < 4; ++mt)
#pragma unroll
        for (int nt = 0; nt < 4; ++nt)
#pragma unroll
            for (int r = 0; r < 4; ++r) {
                int m = m0 + wr * 64 + mt * 16 + g * 4 + r;   // (b, s)
                int n = n0 + wc * 64 + nt * 16 + l15;         // (h, d)
                int b = m >> 11, s = m & 2047, h = n >> 6, d = n & 63;
                __bf16 v = (__bf16)acc[mt][nt][r];
                if (z < 2)
                    QK[(((size_t)(b * NH + h)) * SEQ + s) * DK + d] = v;
                else
                    VTb[(((size_t)(b * NH + h)) * DK + d) * SEQ + s] = v;
            }
}

// Output GEMM: out[M,1024] fp32 = AO[M,1024]bf16 @ Wo^T
__global__ __launch_bounds__(256) void gemm_out(
    const __bf16* __restrict__ AO, const __bf16* __restrict__ wo, float* __restrict__ out)
{
    __shared__ __align__(16) __bf16 sA[128 * 32], sB[128 * 32];
    f32x4 acc[4][4];
    const int m0 = blockIdx.y * 128, n0 = blockIdx.x * 128;
    gemm_tile_compute(AO, wo, m0, n0, DM, sA, sB, acc);

    const int t = threadIdx.x, lane = t & 63, wid = t >> 6;
    const int wr = wid >> 1, wc = wid & 1, g = lane >> 4, l15 = lane & 15;
#pragma unroll
    for (int mt = 0; mt < 4; ++mt)
#pragma unroll
        for (int nt = 0; nt < 4; ++nt)
#pragma unroll
            for (int r = 0; r < 4; ++r) {
                int m = m0 + wr * 64 + mt * 16 + g * 4 + r;
                int n = n0 + wc * 64 + nt * 16 + l15;
                out[(size_t)m * DM + n] = acc[mt][nt][r];
            }
}

// ---------------- RoPE (in-place on Q,K bf16 [B,H,S,dk]) ----------------
__global__ __launch_bounds__(256) void rope_kernel(
    __bf16* __restrict__ Qb, __bf16* __restrict__ Kb, const int* __restrict__ pos)
{
    __shared__ float ctab[32], stab[32];
    const int s = blockIdx.x;       // 0..SEQ-1
    const int t = threadIdx.x;
    if (t < 32) {
        float invf = exp2f(-13.287712379549449f * (float)t * (1.0f / 32.0f));
        float ang = (float)pos[s] * invf;
        float sn, cs;
        sincosf(ang, &sn, &cs);
        ctab[t] = cs; stab[t] = sn;
    }
    __syncthreads();
#pragma unroll
    for (int u = 0; u < 8; ++u) {
        int id = u * 256 + t;              // 0..2047 : [arr][bh][i]
        int i = id & 31;
        int bh = (id >> 5) & 31;
        __bf16* P = (id >> 10) ? Kb : Qb;
        __bf16* p = P + ((size_t)bh * SEQ + s) * DK + i * 2;
        float x1 = (float)p[0], x2 = (float)p[1];
        float c = ctab[i], sn = stab[i];
        p[0] = (__bf16)(x1 * c - x2 * sn);
        p[1] = (__bf16)(x1 * sn + x2 * c);
    }
}

// ---------------- Flash attention ----------------
// grid: (NQT/2, bh). Block x handles q-tiles {x, NQT-1-x} -> constant 33 tile-units.
// LDS tiles: linear [64][64] bf16 (128B rows), XOR-swizzled: phys_chunk = chunk ^ (row&7).
// sP per-wave [16][64], same swizzle; per-wave DS ordering replaces one barrier.
__global__ __launch_bounds__(256) void attn_kernel(
    const __bf16* __restrict__ Qb, const __bf16* __restrict__ Kb,
    const __bf16* __restrict__ VTb, __bf16* __restrict__ AO)
{
    __shared__ __align__(16) __bf16 sK[64 * 64];       // [kv][d] swizzled
    __shared__ __align__(16) __bf16 sV[64 * 64];       // [d][kv] swizzled
    __shared__ __align__(16) __bf16 sP[4 * 16 * 64];   // per-wave [16 q][64 kv] swizzled

    const int x = blockIdx.x, bh = blockIdx.y;
    const int t = threadIdx.x, lane = t & 63, wid = t >> 6;
    const int g = lane >> 4, l15 = lane & 15;

    const size_t baseQK = (size_t)bh * SEQ * DK;
    const size_t baseVT = (size_t)bh * DK * SEQ;
    const int b = bh >> 4, h = bh & 15;

    char* myP = (char*)(sP + wid * 16 * 64);
    f32x4 zero = {0.f, 0.f, 0.f, 0.f};

    for (int ph = 0; ph < 2; ++ph) {
        const int qt = ph ? (NQT - 1 - x) : x;

        // Q fragments for this q-tile
        bf16x8 qf[2];
        {
            const __bf16* qp = Qb + baseQK + (size_t)(qt * 64 + wid * 16 + l15) * DK;
            qf[0] = *(const bf16x8*)(qp + g * 8);
            qf[1] = *(const bf16x8*)(qp + 32 + g * 8);
        }

        f32x4 oacc[4];
#pragma unroll
        for (int dt = 0; dt < 4; ++dt) oacc[dt] = zero;
        float mrow[4], lrow[4];
#pragma unroll
        for (int r = 0; r < 4; ++r) { mrow[r] = -3e38f; lrow[r] = 0.f; }

        const char* Kt0 = (const char*)(Kb + baseQK);
        const char* Vt0 = (const char*)(VTb + baseVT);

        for (int kt = 0; kt <= qt; ++kt) {
            __syncthreads();
            // stage K tile (contiguous 8KB) + V^T tile (64 rows, stride SEQ*2B), swizzled
            const char* Kt = Kt0 + (size_t)kt * 64 * 128;
            const char* Vt = Vt0 + (size_t)kt * 128;
#pragma unroll
            for (int cc = 0; cc < 2; ++cc) {
                int c = t + cc * 256;            // 0..511 chunk slots
                int r = c >> 3, p = c & 7;       // row, logical 16B chunk
                int pp = p ^ (r & 7);            // physical chunk
                *(ushort8*)((char*)sK + r * 128 + pp * 16) =
                    *(const ushort8*)(Kt + (size_t)r * 128 + p * 16);
                *(ushort8*)((char*)sV + r * 128 + pp * 16) =
                    *(const ushort8*)(Vt + (size_t)r * (SEQ * 2) + p * 16);
            }
            __syncthreads();

            // S = Q K^T (scaled); rows of sK at same column chunk -> swizzle spreads banks
            f32x4 sacc[4];
#pragma unroll
            for (int nt = 0; nt < 4; ++nt) {
                sacc[nt] = zero;
#pragma unroll
                for (int ks = 0; ks < 2; ++ks) {
                    int row = nt * 16 + l15;
                    bf16x8 kf = *(const bf16x8*)((const char*)sK + row * 128 +
                                                 ((ks * 64 + g * 16) ^ ((row & 7) << 4)));
                    sacc[nt] = __builtin_amdgcn_mfma_f32_16x16x32_bf16(qf[ks], kf, sacc[nt], 0, 0, 0);
                }
            }
#pragma unroll
            for (int nt = 0; nt < 4; ++nt)
#pragma unroll
                for (int r = 0; r < 4; ++r) {
                    float sv = sacc[nt][r] * 0.125f;
                    if (kt == qt) {
                        int c_local = nt * 16 + l15;
                        int q_local = wid * 16 + g * 4 + r;
                        if (c_local > q_local) sv = -3e38f;
                    }
                    sacc[nt][r] = sv;
                }

            // online softmax per row (row lives on 16 lanes of group g)
#pragma unroll
            for (int r = 0; r < 4; ++r) {
                float tm = fmaxf(fmaxf(sacc[0][r], sacc[1][r]), fmaxf(sacc[2][r], sacc[3][r]));
#pragma unroll
                for (int msk = 1; msk < 16; msk <<= 1) tm = fmaxf(tm, __shfl_xor(tm, msk));
                float mnew = fmaxf(mrow[r], tm);
                float sc = __expf(mrow[r] - mnew);
                float rs = 0.f;
#pragma unroll
                for (int nt = 0; nt < 4; ++nt) {
                    float p = __expf(sacc[nt][r] - mnew);
                    sacc[nt][r] = p;
                    rs += p;
                }
#pragma unroll
                for (int msk = 1; msk < 16; msk <<= 1) rs += __shfl_xor(rs, msk);
                lrow[r] = lrow[r] * sc + rs;
                mrow[r] = mnew;
#pragma unroll
                for (int dt = 0; dt < 4; ++dt) oacc[dt][r] *= sc;
            }

            // P -> per-wave LDS (swizzled); same-wave DS ops are in-order -> no barrier
#pragma unroll
            for (int nt = 0; nt < 4; ++nt)
#pragma unroll
                for (int r = 0; r < 4; ++r) {
                    int row = g * 4 + r;
                    *(__bf16*)(myP + row * 128 +
                               ((nt * 32 + l15 * 2) ^ ((row & 7) << 4))) = (__bf16)sacc[nt][r];
                }

#pragma unroll
            for (int ks = 0; ks < 2; ++ks) {
                bf16x8 pf = *(const bf16x8*)(myP + l15 * 128 +
                                             ((ks * 64 + g * 16) ^ ((l15 & 7) << 4)));
#pragma unroll
                for (int dt = 0; dt < 4; ++dt) {
                    int row = dt * 16 + l15;
                    bf16x8 vf = *(const bf16x8*)((const char*)sV + row * 128 +
                                                 ((ks * 64 + g * 16) ^ ((row & 7) << 4)));
                    oacc[dt] = __builtin_amdgcn_mfma_f32_16x16x32_bf16(pf, vf, oacc[dt], 0, 0, 0);
                }
            }
        }

        // epilogue: O /= l, write to AO [b][s][h*64+d]
#pragma unroll
        for (int r = 0; r < 4; ++r) {
            float inv = 1.0f / lrow[r];
            int srow = qt * 64 + wid * 16 + g * 4 + r;
            size_t obase = ((size_t)b * SEQ + srow) * DM + h * DK;
#pragma unroll
            for (int dt = 0; dt < 4; ++dt)
                AO[obase + dt * 16 + l15] = (__bf16)(oacc[dt][r] * inv);
        }
    }
}

// ---------------- launch ----------------
extern "C" void kernel_launch(void* const* d_in, const int* in_sizes, int n_in,
                              void* d_out, int out_size, void* d_ws, size_t ws_size,
                              hipStream_t stream) {
    (void)in_sizes; (void)n_in; (void)out_size; (void)ws_size;
    const float* x  = (const float*)d_in[0];
    const int*  pos = (const int*)d_in[1];
    const float* Wq = (const float*)d_in[2];
    const float* Wk = (const float*)d_in[3];
    const float* Wv = (const float*)d_in[4];
    const float* Wo = (const float*)d_in[5];
    float* out = (float*)d_out;

    char* ws = (char*)d_ws;
    __bf16* xb  = (__bf16*)ws; ws += (size_t)M_TOT * DM * 2;
    __bf16* wqb = (__bf16*)ws; ws += (size_t)DM * DM * 2;
    __bf16* wkb = (__bf16*)ws; ws += (size_t)DM * DM * 2;
    __bf16* wvb = (__bf16*)ws; ws += (size_t)DM * DM * 2;
    __bf16* wob = (__bf16*)ws; ws += (size_t)DM * DM * 2;
    __bf16* Qb  = (__bf16*)ws; ws += (size_t)BH * SEQ * DK * 2;
    __bf16* Kb  = (__bf16*)ws; ws += (size_t)BH * SEQ * DK * 2;
    __bf16* VTb = (__bf16*)ws; ws += (size_t)BH * SEQ * DK * 2;
    __bf16* AOb = (__bf16*)ws; ws += (size_t)M_TOT * DM * 2;

    const int nx = M_TOT * DM, nw = DM * DM;
    cvt_kernel<<<nx / 4 / 256, 256, 0, stream>>>(x, xb, nx);
    cvt4_kernel<<<dim3(nw / 4 / 256, 4), 256, 0, stream>>>(Wq, Wk, Wv, Wo, wqb, wkb, wvb, wob, nw);

    gemm_qkv<<<dim3(DM / 128, M_TOT / 128, 3), 256, 0, stream>>>(xb, wqb, wkb, wvb, Qb, Kb, VTb);
    rope_kernel<<<SEQ, 256, 0, stream>>>(Qb, Kb, pos);
    attn_kernel<<<dim3(NQT / 2, BH), 256, 0, stream>>>(Qb, Kb, VTb, AOb);
    gemm_out<<<dim3(DM / 128, M_TOT / 128), 256, 0, stream>>>(AOb, wob, out);
}